// Round 8
// baseline (181.843 us; speedup 1.0000x reference)
//
#include <hip/hip_runtime.h>
#include <stdint.h>
#include <stddef.h>

typedef __attribute__((ext_vector_type(8))) short s16x8;
typedef __attribute__((ext_vector_type(4))) short s16x4;
typedef __attribute__((ext_vector_type(4))) float f32x4;

#define B_  2
#define T_  2048
#define E_  1024
#define H_  16
#define E3_ 3072

// fp32 -> bf16, round-to-nearest-even
__device__ __forceinline__ short f2bf(float f) {
  union { float f; uint32_t u; } v; v.f = f;
  uint32_t u = v.u;
  return (short)((u + 0x7FFFu + ((u >> 16) & 1u)) >> 16);
}

__device__ __forceinline__ uint32_t fbits(float f) {
  union { float f; uint32_t u; } v; v.f = f; return v.u;
}

// async global->LDS, 16B per lane; lds dest = wave-uniform base + lane*16
__device__ __forceinline__ void gload_lds16(const short* g, short* l) {
  __builtin_amdgcn_global_load_lds(
      (__attribute__((address_space(1))) void*)(const_cast<short*>(g)),
      (__attribute__((address_space(3))) void*)(l), 16, 0, 0);
}

// ---------------- merged cast kernel (x, w_qkv, w_proj in one launch) -------
// Q-rows of w_qkv (first E rows) pre-scaled by log2(e)/8 so attention can
// call exp2f directly on MFMA output. Also zeroes the attn work-queue counter.
__global__ void castk_all(const float* __restrict__ x, const float* __restrict__ wqkv,
                          const float* __restrict__ wproj, short* __restrict__ xb,
                          short* __restrict__ wqkvb, short* __restrict__ wprojb,
                          int* __restrict__ ctr) {
  const int bid = blockIdx.x;
  if (bid == 0 && threadIdx.x == 0) *ctr = 0;
  const float* in; short* out; int i; float sc = 1.0f;
  if (bid < 4096)      { in = x;     out = xb;     i = bid * 256 + threadIdx.x; }
  else if (bid < 7168) { in = wqkv;  out = wqkvb;  i = (bid - 4096) * 256 + threadIdx.x;
                         if (i < 262144) sc = 0.18033688011112042f; }
  else                 { in = wproj; out = wprojb; i = (bid - 7168) * 256 + threadIdx.x; }
  const float4 v = ((const float4*)in)[i];
  s16x4 o;
  o[0] = f2bf(v.x * sc); o[1] = f2bf(v.y * sc);
  o[2] = f2bf(v.z * sc); o[3] = f2bf(v.w * sc);
  ((s16x4*)out)[i] = o;
}

// ---------------- NT GEMM: C[M,N] = A[M,K] * B[N,K]^T (bf16 in, fp32 acc) ---
// MODE 0: fp32 output, plain. MODE 2: qkv mode — bf16 output; V columns
// (col >= 2E) are written TRANSPOSED into vt[b,h,d,t] (packed s16x4 over 4
// consecutive t), Q/K columns go to the qkv buffer. Fuses the old vtrans.
template <int MODE>
__global__ void gemm_nt_128(const short* __restrict__ A, const short* __restrict__ B,
                            void* __restrict__ Cv, short* __restrict__ vt,
                            int M, int N, int K) {
  __shared__ short As[128 * 32];
  __shared__ short Bs[128 * 32];
  const int tid  = threadIdx.x;
  const int lane = tid & 63;
  const int w    = tid >> 6;
  const int quad = lane >> 4;
  const int l16  = lane & 15;
  const int wm   = (w >> 1) * 64;
  const int wn   = (w & 1) * 64;
  const int bm   = blockIdx.y * 128;
  const int bn   = blockIdx.x * 128;

  f32x4 acc[4][4];
#pragma unroll
  for (int i = 0; i < 4; i++)
#pragma unroll
    for (int j = 0; j < 4; j++) acc[i][j] = (f32x4){0.f, 0.f, 0.f, 0.f};

  const int srow = w * 32 + (lane >> 2);
  const int scol = (lane & 3) * 8;
  const short* gA = A + (size_t)(bm + srow) * K + scol;
  const short* gB = B + (size_t)(bn + srow) * K + scol;
  short* lA = As + (w * 32) * 32;
  short* lB = Bs + (w * 32) * 32;

  for (int k0 = 0; k0 < K; k0 += 32) {
    __syncthreads();
    gload_lds16(gA + k0,          lA);
    gload_lds16(gA + 16 * K + k0, lA + 16 * 32);
    gload_lds16(gB + k0,          lB);
    gload_lds16(gB + 16 * K + k0, lB + 16 * 32);
    __syncthreads();

    s16x8 a[4], b[4];
#pragma unroll
    for (int i = 0; i < 4; i++)
      a[i] = *(const s16x8*)&As[(wm + i * 16 + l16) * 32 + quad * 8];
#pragma unroll
    for (int j = 0; j < 4; j++)
      b[j] = *(const s16x8*)&Bs[(wn + j * 16 + l16) * 32 + quad * 8];
#pragma unroll
    for (int i = 0; i < 4; i++)
#pragma unroll
      for (int j = 0; j < 4; j++)
        acc[i][j] = __builtin_amdgcn_mfma_f32_16x16x32_bf16(a[i], b[j], acc[i][j], 0, 0, 0);
  }

  if (MODE == 2 && bn >= 2 * E_) {
    // V block: write transposed to vt[b,h,d,t], 4 consecutive t per store
#pragma unroll
    for (int i = 0; i < 4; i++) {
      const int token = bm + wm + i * 16 + quad * 4;
      const int bb = token >> 11, t = token & (T_ - 1);
#pragma unroll
      for (int j = 0; j < 4; j++) {
        const int col = bn + wn + j * 16 + l16 - 2 * E_;  // h*64 + d
        s16x4 pk;
#pragma unroll
        for (int r = 0; r < 4; r++) pk[r] = f2bf(acc[i][j][r]);
        *(s16x4*)&vt[((size_t)(bb * H_ + (col >> 6)) * 64 + (col & 63)) * T_ + t] = pk;
      }
    }
  } else {
#pragma unroll
    for (int i = 0; i < 4; i++) {
      const int row0 = bm + wm + i * 16 + quad * 4;
#pragma unroll
      for (int j = 0; j < 4; j++) {
        const int col = bn + wn + j * 16 + l16;
#pragma unroll
        for (int r = 0; r < 4; r++) {
          const size_t idx = (size_t)(row0 + r) * N + col;
          if (MODE == 2) ((short*)Cv)[idx] = f2bf(acc[i][j][r]);
          else           ((float*)Cv)[idx] = acc[i][j][r];
        }
      }
    }
  }
}

// ---------------- flash attention -------------------------------------------
// R8 = EXACT R4 inner body (best verified: in-register P transpose via
// cvt_pk+permlane, sigma K-store permutation, tau diag mask, double-buffered
// K/V staging, single SM region, setprio around MFMA clusters) with the
// static triangular grid replaced by a DYNAMIC LPT WORK QUEUE:
//  * R7's counters showed the static 4-blocks/CU grid has no refill: per-CU
//    concurrent lifetimes {32,17,16,1} steps -> Occupancy 25.6% (8.2/16
//    waves avg), the last ~15 steps of the long block run at 1-2 blocks/CU.
//  * Grid = 768 persistent blocks (3/CU). 1024 items = (bh, qt), pulled via
//    global atomicAdd, LONGEST-FIRST (qt = 31 - item/32). 256 spare items
//    refill CUs as short items finish; the tail is the shortest items.
//    Items are self-contained (no-max softmax -> no cross-block combine).
//  * Queue counter lives in the dead V-third of the qkv buffer (columns
//    2048..3071 are never written by the GEMM); zeroed by castk_all each
//    launch, so rocprof replays and graph re-execution stay correct.
__global__ void __launch_bounds__(256, 4)
attn_kernel(const short* __restrict__ qkv, const short* __restrict__ vt,
            short* __restrict__ attout, int* __restrict__ ctr) {
  __shared__ short Ks[2][64 * 64];  // [kv_pos][d], 16B-chunk swizzled, sigma row order
  __shared__ short Vs[2][64 * 64];  // [d][kv], 16B-chunk swizzled, linear kv
  __shared__ int ibuf;
  const int tid  = threadIdx.x;
  const int lane = tid & 63;
  const int w    = tid >> 6;
  const int quad = lane >> 4;
  const int l16  = lane & 15;
  const float NEG_INF = -__builtin_inff();

  const int srl = lane >> 3;
  const int sgc = ((lane & 7) ^ srl) * 8;
  const int swz = (l16 & 7);

  s16x8 ones;
#pragma unroll
  for (int i = 0; i < 8; i++) ones[i] = (short)0x3F80;  // bf16 1.0

  for (;;) {
    if (tid == 0) ibuf = atomicAdd(ctr, 1);
    __syncthreads();
    const int item = ibuf;
    if (item >= 1024) break;  // block-uniform exit
    // longest-first: qt descends as the queue drains
    const int qt = 31 - (item >> 5);
    const int bh = item & 31;
    const int b = bh >> 4, h = bh & 15;
    const int q0b = qt * 64;
    const int q0w = q0b + w * 16;

    const short* gK = qkv + (size_t)(b * T_) * E3_ + E_ + h * 64 + sgc;
    const short* gV = vt + (size_t)(bh * 64) * T_ + sgc;

    auto stage = [&](int kv0s, int bf) {
#pragma unroll
      for (int i = 0; i < 2; i++) {
        const int r8 = w * 16 + i * 8;          // LDS row-chunk base
        const int rowp = r8 + srl;              // LDS row position
        // sigma: swap bits 2,3 of row index (K source only; V stays linear)
        const int rowk = (rowp & ~12) | ((rowp & 4) << 1) | ((rowp & 8) >> 1);
        gload_lds16(gK + (size_t)(kv0s + rowk) * E3_, &Ks[bf][r8 * 64]);
        gload_lds16(gV + (size_t)rowp * T_ + kv0s,    &Vs[bf][r8 * 64]);
      }
    };

    // Q B-fragments (pre-scaled): B[n=l16][k=quad*8+j], two k-chunks
    const short* qbase = qkv + (size_t)(b * T_ + q0w + l16) * E3_ + h * 64 + quad * 8;
    const s16x8 qf0 = *(const s16x8*)(qbase);
    const s16x8 qf1 = *(const s16x8*)(qbase + 32);

    f32x4 o[4]; f32x4 ol = (f32x4){0.f, 0.f, 0.f, 0.f};
#pragma unroll
    for (int j = 0; j < 4; j++) o[j] = (f32x4){0.f, 0.f, 0.f, 0.f};

    // prologue: stage kv tile 0 into buffer 0 (also orders ibuf WAR)
    stage(0, 0);
    __syncthreads();

    for (int kv0 = 0, g = 0; kv0 <= q0b; kv0 += 64, g++) {
      const int cur = g & 1;

      // K A-fragments for this step
      s16x8 kf[2][4];
#pragma unroll
      for (int c = 0; c < 2; c++)
#pragma unroll
        for (int j = 0; j < 4; j++)
          kf[c][j] = *(const s16x8*)&Ks[cur][(j * 16 + l16) * 64 + (((c * 4 + quad) ^ swz) * 8)];

      // prefetch next tile's DMA (hidden under this step's compute)
      if (kv0 + 64 <= q0b) stage(kv0 + 64, cur ^ 1);

      // S^T tile: s[j][r] = score[kv_pos = 16j+4quad+r][q = q0w+l16]
      f32x4 s[4];
#pragma unroll
      for (int j = 0; j < 4; j++) s[j] = (f32x4){0.f, 0.f, 0.f, 0.f};
      __builtin_amdgcn_s_setprio(1);
#pragma unroll
      for (int c = 0; c < 2; c++)
#pragma unroll
        for (int j = 0; j < 4; j++)
          s[j] = __builtin_amdgcn_mfma_f32_16x16x32_bf16(kf[c][j], c == 0 ? qf0 : qf1, s[j], 0, 0, 0);
      __builtin_amdgcn_s_setprio(0);

      // mask only on the diagonal step; actual kv = 16j + 4*tau(quad) + r
      if (kv0 == q0b) {
        const int tq4 = ((quad & 1) << 3) | ((quad >> 1) << 2);
#pragma unroll
        for (int j = 0; j < 4; j++)
#pragma unroll
          for (int r = 0; r < 4; r++)
            if (j * 16 + tq4 + r > w * 16 + l16) s[j][r] = NEG_INF;
      }

      // exp2 in place
#pragma unroll
      for (int j = 0; j < 4; j++) {
        s[j][0] = exp2f(s[j][0]); s[j][1] = exp2f(s[j][1]);
        s[j][2] = exp2f(s[j][2]); s[j][3] = exp2f(s[j][3]);
      }

      // pack row pairs -> bf16 dwords (dst.lo = src0)
      int dj[4][2];
#pragma unroll
      for (int j = 0; j < 4; j++) {
        asm("v_cvt_pk_bf16_f32 %0, %1, %2" : "=v"(dj[j][0]) : "v"(s[j][0]), "v"(s[j][1]));
        asm("v_cvt_pk_bf16_f32 %0, %1, %2" : "=v"(dj[j][1]) : "v"(s[j][2]), "v"(s[j][3]));
      }

      // 2x permlane32_swap per kv32 chunk -> B-operand fragments in actual-kv order
      s16x8 F[2];
#pragma unroll
      for (int c = 0; c < 2; c++) {
        int x0 = dj[2 * c][0], y0 = dj[2 * c + 1][0];
        int x1 = dj[2 * c][1], y1 = dj[2 * c + 1][1];
        asm("v_permlane32_swap_b32 %0, %1" : "+v"(x0), "+v"(y0));
        asm("v_permlane32_swap_b32 %0, %1" : "+v"(x1), "+v"(y1));
        union { int i4[4]; s16x8 v; } u;
        u.i4[0] = x0; u.i4[1] = x1; u.i4[2] = y0; u.i4[3] = y1;
        F[c] = u.v;
      }

      // O^T += V^T P^T ; row sums via ones-MFMA (every reg = sum of lane's q)
      __builtin_amdgcn_s_setprio(1);
#pragma unroll
      for (int c = 0; c < 2; c++) {
        ol = __builtin_amdgcn_mfma_f32_16x16x32_bf16(ones, F[c], ol, 0, 0, 0);
#pragma unroll
        for (int j = 0; j < 4; j++) {
          const s16x8 vf = *(const s16x8*)&Vs[cur][(j * 16 + l16) * 64 + (((c * 4 + quad) ^ swz) * 8)];
          o[j] = __builtin_amdgcn_mfma_f32_16x16x32_bf16(vf, F[c], o[j], 0, 0, 0);
        }
      }
      __builtin_amdgcn_s_setprio(0);

      __syncthreads();  // drains prefetch (covered by compute) + WAR fence
    }

    // epilogue: lane owns q = q0w + l16; o[j][r] = O[q][d = 16j+4quad+r]
    const float inv = 1.0f / ol[0];
    const int q = q0w + l16;
    short* ob = attout + ((size_t)(b * T_ + q) * H_ + h) * 64 + quad * 4;
#pragma unroll
    for (int j = 0; j < 4; j++) {
      s16x4 pk;
#pragma unroll
      for (int r = 0; r < 4; r++) pk[r] = f2bf(o[j][r] * inv);
      *(s16x4*)&ob[16 * j] = pk;
    }
  }
}

// ---------------- launch -----------------------------------------------------
extern "C" void kernel_launch(void* const* d_in, const int* in_sizes, int n_in,
                              void* d_out, int out_size, void* d_ws, size_t ws_size,
                              hipStream_t stream) {
  const float* x     = (const float*)d_in[0];   // [4096, 1024] fp32
  const float* wqkv  = (const float*)d_in[1];   // [3072, 1024] fp32
  const float* wproj = (const float*)d_in[2];   // [1024, 1024] fp32

  if (ws_size < 58720256u) return;
  short* ws     = (short*)d_ws;
  short* xb     = ws;                    // 4096*1024
  short* wqkvb  = xb + 4194304;          // 3072*1024
  short* wprojb = wqkvb + 3145728;       // 1024*1024
  short* qkv    = wprojb + 1048576;      // 4096*3072 (V third unused)
  short* vt     = qkv + 12582912;        // 2*16*64*2048
  short* attb   = vt + 4194304;          // 4096*1024
  // queue counter in the dead V-third of qkv row 0 (cols 2048.. never written)
  int* ctr      = (int*)(qkv + 2 * E_);

  castk_all<<<8192, 256, 0, stream>>>(x, wqkv, wproj, xb, wqkvb, wprojb, ctr);
  gemm_nt_128<2><<<dim3(24, 32), 256, 0, stream>>>(xb, wqkvb, qkv, vt, 4096, 3072, 1024);
  attn_kernel<<<dim3(768), 256, 0, stream>>>(qkv, vt, attb, ctr);
  gemm_nt_128<0><<<dim3(8, 32), 256, 0, stream>>>(attb, wprojb, d_out, nullptr, 4096, 1024, 1024);
}

// Round 9
// 176.117 us; speedup vs baseline: 1.0325x; 1.0325x over previous
//
#include <hip/hip_runtime.h>
#include <stdint.h>
#include <stddef.h>

typedef __attribute__((ext_vector_type(8))) short s16x8;
typedef __attribute__((ext_vector_type(4))) short s16x4;
typedef __attribute__((ext_vector_type(4))) float f32x4;

#define B_  2
#define T_  2048
#define E_  1024
#define H_  16
#define E3_ 3072

// fp32 -> bf16, round-to-nearest-even
__device__ __forceinline__ short f2bf(float f) {
  union { float f; uint32_t u; } v; v.f = f;
  uint32_t u = v.u;
  return (short)((u + 0x7FFFu + ((u >> 16) & 1u)) >> 16);
}

// async global->LDS, 16B per lane; lds dest = wave-uniform base + lane*16
__device__ __forceinline__ void gload_lds16(const short* g, short* l) {
  __builtin_amdgcn_global_load_lds(
      (__attribute__((address_space(1))) void*)(const_cast<short*>(g)),
      (__attribute__((address_space(3))) void*)(l), 16, 0, 0);
}

// ---------------- merged cast kernel (x, w_qkv, w_proj in one launch) -------
// Q-rows of w_qkv (first E rows) pre-scaled by log2(e)/8 so attention can
// call exp2f directly on MFMA output.
__global__ void castk_all(const float* __restrict__ x, const float* __restrict__ wqkv,
                          const float* __restrict__ wproj, short* __restrict__ xb,
                          short* __restrict__ wqkvb, short* __restrict__ wprojb) {
  const int bid = blockIdx.x;
  const float* in; short* out; int i; float sc = 1.0f;
  if (bid < 4096)      { in = x;     out = xb;     i = bid * 256 + threadIdx.x; }
  else if (bid < 7168) { in = wqkv;  out = wqkvb;  i = (bid - 4096) * 256 + threadIdx.x;
                         if (i < 262144) sc = 0.18033688011112042f; }
  else                 { in = wproj; out = wprojb; i = (bid - 7168) * 256 + threadIdx.x; }
  const float4 v = ((const float4*)in)[i];
  s16x4 o;
  o[0] = f2bf(v.x * sc); o[1] = f2bf(v.y * sc);
  o[2] = f2bf(v.z * sc); o[3] = f2bf(v.w * sc);
  ((s16x4*)out)[i] = o;
}

// ---------------- NT GEMM: C[M,N] = A[M,K] * B[N,K]^T (bf16 in, fp32 acc) ---
template <int MODE>
__global__ void gemm_nt_128(const short* __restrict__ A, const short* __restrict__ B,
                            void* __restrict__ Cv, short* __restrict__ vt,
                            int M, int N, int K) {
  __shared__ short As[128 * 32];
  __shared__ short Bs[128 * 32];
  const int tid  = threadIdx.x;
  const int lane = tid & 63;
  const int w    = tid >> 6;
  const int quad = lane >> 4;
  const int l16  = lane & 15;
  const int wm   = (w >> 1) * 64;
  const int wn   = (w & 1) * 64;
  const int bm   = blockIdx.y * 128;
  const int bn   = blockIdx.x * 128;

  f32x4 acc[4][4];
#pragma unroll
  for (int i = 0; i < 4; i++)
#pragma unroll
    for (int j = 0; j < 4; j++) acc[i][j] = (f32x4){0.f, 0.f, 0.f, 0.f};

  const int srow = w * 32 + (lane >> 2);
  const int scol = (lane & 3) * 8;
  const short* gA = A + (size_t)(bm + srow) * K + scol;
  const short* gB = B + (size_t)(bn + srow) * K + scol;
  short* lA = As + (w * 32) * 32;
  short* lB = Bs + (w * 32) * 32;

  for (int k0 = 0; k0 < K; k0 += 32) {
    __syncthreads();
    gload_lds16(gA + k0,          lA);
    gload_lds16(gA + 16 * K + k0, lA + 16 * 32);
    gload_lds16(gB + k0,          lB);
    gload_lds16(gB + 16 * K + k0, lB + 16 * 32);
    __syncthreads();

    s16x8 a[4], b[4];
#pragma unroll
    for (int i = 0; i < 4; i++)
      a[i] = *(const s16x8*)&As[(wm + i * 16 + l16) * 32 + quad * 8];
#pragma unroll
    for (int j = 0; j < 4; j++)
      b[j] = *(const s16x8*)&Bs[(wn + j * 16 + l16) * 32 + quad * 8];
#pragma unroll
    for (int i = 0; i < 4; i++)
#pragma unroll
      for (int j = 0; j < 4; j++)
        acc[i][j] = __builtin_amdgcn_mfma_f32_16x16x32_bf16(a[i], b[j], acc[i][j], 0, 0, 0);
  }

  if (MODE == 2 && bn >= 2 * E_) {
#pragma unroll
    for (int i = 0; i < 4; i++) {
      const int token = bm + wm + i * 16 + quad * 4;
      const int bb = token >> 11, t = token & (T_ - 1);
#pragma unroll
      for (int j = 0; j < 4; j++) {
        const int col = bn + wn + j * 16 + l16 - 2 * E_;  // h*64 + d
        s16x4 pk;
#pragma unroll
        for (int r = 0; r < 4; r++) pk[r] = f2bf(acc[i][j][r]);
        *(s16x4*)&vt[((size_t)(bb * H_ + (col >> 6)) * 64 + (col & 63)) * T_ + t] = pk;
      }
    }
  } else {
#pragma unroll
    for (int i = 0; i < 4; i++) {
      const int row0 = bm + wm + i * 16 + quad * 4;
#pragma unroll
      for (int j = 0; j < 4; j++) {
        const int col = bn + wn + j * 16 + l16;
#pragma unroll
        for (int r = 0; r < 4; r++) {
          const size_t idx = (size_t)(row0 + r) * N + col;
          if (MODE == 2) ((short*)Cv)[idx] = f2bf(acc[i][j][r]);
          else           ((float*)Cv)[idx] = acc[i][j][r];
        }
      }
    }
  }
}

// ---------------- flash attention -------------------------------------------
// R9: LDS-traffic + balance redesign on the R4 machinery (sigma K-store perm,
// tau diag mask, cvt_pk+permlane in-register P transpose all carried over):
//  * 32 q/wave x 4 waves = 128-q blocks: kf/vf b128 reads reused across two
//    q-subtiles -> LDS bytes per unit work HALVED (R8's analysis showed the
//    LDS pipe ~80-100% saturated in the 16q structure). Staging also halves.
//  * kv-split items: Q>=8 tiles split into head [0,Q+1) / tail [Q+1,2Q+2)
//    (each Q+1 steps, <=16); Q<=7 full (<=16 steps). Partials are additive
//    (no-max softmax): heads/tails write raw f32 O to d_out-as-scratch (free
//    until proj GEMM) + row-sums to the dead V-third of qkv; att_norm
//    combines rows q in [1024,2048).
//  * itab orders the 24 items/bh so every CU's 3 blocks sum to EXACTLY 34
//    steps (768 blocks = 3/CU, all co-resident; stripe k = items {k,k+8,k+16}
//    with lengths summing 34 for all k).
//  * bid = item*32 + bh -> XCD = bh%8 preserved (R8: queue broke this, 7x
//    refetch). Scratch is also XCD-local by bh.
__device__ const unsigned char itab[24] = {
  // (kind<<4)|Q : kind 0=full,1=head,2=tail. Stripe sums all = 34 steps.
  0x1F, 0x07, 0x1E, 0x2E, 0x2D, 0x2C, 0x06, 0x2B,
  0x2F, 0x1D, 0x1C, 0x1A, 0x2A, 0x1B, 0x19, 0x05,
  0x00, 0x01, 0x02, 0x03, 0x18, 0x28, 0x29, 0x04
};

__global__ void __launch_bounds__(256, 3)
attn_kernel(short* qkv, const short* __restrict__ vt,
            short* __restrict__ attout, float* __restrict__ scr) {
  __shared__ short Ks[2][64 * 64];  // [kv_pos][d], sigma row order
  __shared__ short Vs[2][64 * 64];  // [d][kv], linear kv
  const int tid  = threadIdx.x;
  const int lane = tid & 63;
  const int w    = tid >> 6;
  const int quad = lane >> 4;
  const int l16  = lane & 15;
  const int bh = blockIdx.x & 31;
  const int b = bh >> 4, h = bh & 15;
  const int e = itab[blockIdx.x >> 5];
  const int Q = e & 15, kind = e >> 4;
  const int t0 = (kind == 2) ? (Q + 1) : 0;
  const int t1 = (kind == 1) ? Q : (2 * Q + 1);
  const int q0w = Q * 128 + w * 32;
  const int tp  = 2 * Q + (w >> 1);    // this wave's partial (diag) tile
  const int woff = (w & 1) * 32;       // q offset within the diag tile
  const float NEG_INF = -__builtin_inff();

  const int srl = lane >> 3;
  const int sgc = ((lane & 7) ^ srl) * 8;
  const short* gK = qkv + (size_t)(b * T_) * E3_ + E_ + h * 64 + sgc;
  const short* gV = vt + (size_t)(bh * 64) * T_ + sgc;
  const int swz = (l16 & 7);

  s16x8 ones;
#pragma unroll
  for (int i = 0; i < 8; i++) ones[i] = (short)0x3F80;  // bf16 1.0

  auto stage = [&](int kv0s, int bf) {
#pragma unroll
    for (int i = 0; i < 2; i++) {
      const int r8 = w * 16 + i * 8;
      const int rowp = r8 + srl;
      // sigma: swap bits 2,3 of row index (K source only; V stays linear)
      const int rowk = (rowp & ~12) | ((rowp & 4) << 1) | ((rowp & 8) >> 1);
      gload_lds16(gK + (size_t)(kv0s + rowk) * E3_, &Ks[bf][r8 * 64]);
      gload_lds16(gV + (size_t)rowp * T_ + kv0s,    &Vs[bf][r8 * 64]);
    }
  };

  // Q B-fragments for this wave's 32 rows (pre-scaled by log2e/8)
  s16x8 qf[2][2];
#pragma unroll
  for (int sub = 0; sub < 2; sub++) {
    const short* qbase = qkv + (size_t)(b * T_ + q0w + sub * 16 + l16) * E3_ + h * 64 + quad * 8;
    qf[sub][0] = *(const s16x8*)(qbase);
    qf[sub][1] = *(const s16x8*)(qbase + 32);
  }

  f32x4 o[2][4], ol[2];
#pragma unroll
  for (int sub = 0; sub < 2; sub++) {
    ol[sub] = (f32x4){0.f, 0.f, 0.f, 0.f};
#pragma unroll
    for (int j = 0; j < 4; j++) o[sub][j] = (f32x4){0.f, 0.f, 0.f, 0.f};
  }

  stage(t0 * 64, 0);
  __syncthreads();

#pragma unroll 1
  for (int t = t0; t <= t1; t++) {
    const int cur = (t - t0) & 1;
    if (t + 1 <= t1) stage((t + 1) * 64, cur ^ 1);

    if (t <= tp) {  // wave-uniform; tiles beyond the diag are fully masked
      // S^T: s[sub][j][r] = score[kv_pos=64t+16j+4quad+r][q=q0w+sub*16+l16]
      f32x4 s[2][4];
#pragma unroll
      for (int sub = 0; sub < 2; sub++)
#pragma unroll
        for (int j = 0; j < 4; j++) s[sub][j] = (f32x4){0.f, 0.f, 0.f, 0.f};

      __builtin_amdgcn_s_setprio(1);
#pragma unroll
      for (int c = 0; c < 2; c++) {
        s16x8 kf[4];  // reused for both q-subtiles
#pragma unroll
        for (int j = 0; j < 4; j++)
          kf[j] = *(const s16x8*)&Ks[cur][(j * 16 + l16) * 64 + (((c * 4 + quad) ^ swz) * 8)];
#pragma unroll
        for (int sub = 0; sub < 2; sub++)
#pragma unroll
          for (int j = 0; j < 4; j++)
            s[sub][j] = __builtin_amdgcn_mfma_f32_16x16x32_bf16(kf[j], qf[sub][c], s[sub][j], 0, 0, 0);
      }
      __builtin_amdgcn_s_setprio(0);

      // diag mask; actual kv local = 16j + 4*tau(quad) + r
      if (t == tp) {
        const int tq4 = ((quad & 1) << 3) | ((quad >> 1) << 2);
#pragma unroll
        for (int sub = 0; sub < 2; sub++)
#pragma unroll
          for (int j = 0; j < 4; j++)
#pragma unroll
            for (int r = 0; r < 4; r++)
              if (j * 16 + tq4 + r > woff + sub * 16 + l16) s[sub][j][r] = NEG_INF;
      }

      // exp2 + pack -> permlane -> B-operand fragments F[sub][c]
      s16x8 F[2][2];
#pragma unroll
      for (int sub = 0; sub < 2; sub++) {
#pragma unroll
        for (int j = 0; j < 4; j++) {
          s[sub][j][0] = exp2f(s[sub][j][0]); s[sub][j][1] = exp2f(s[sub][j][1]);
          s[sub][j][2] = exp2f(s[sub][j][2]); s[sub][j][3] = exp2f(s[sub][j][3]);
        }
#pragma unroll
        for (int c = 0; c < 2; c++) {
          int x0, x1, y0, y1;
          asm("v_cvt_pk_bf16_f32 %0, %1, %2" : "=v"(x0) : "v"(s[sub][2 * c][0]), "v"(s[sub][2 * c][1]));
          asm("v_cvt_pk_bf16_f32 %0, %1, %2" : "=v"(x1) : "v"(s[sub][2 * c][2]), "v"(s[sub][2 * c][3]));
          asm("v_cvt_pk_bf16_f32 %0, %1, %2" : "=v"(y0) : "v"(s[sub][2 * c + 1][0]), "v"(s[sub][2 * c + 1][1]));
          asm("v_cvt_pk_bf16_f32 %0, %1, %2" : "=v"(y1) : "v"(s[sub][2 * c + 1][2]), "v"(s[sub][2 * c + 1][3]));
          asm("v_permlane32_swap_b32 %0, %1" : "+v"(x0), "+v"(y0));
          asm("v_permlane32_swap_b32 %0, %1" : "+v"(x1), "+v"(y1));
          union { int i4[4]; s16x8 v; } u;
          u.i4[0] = x0; u.i4[1] = x1; u.i4[2] = y0; u.i4[3] = y1;
          F[sub][c] = u.v;
        }
      }

      // O^T += V^T P^T ; vf reused for both q-subtiles; row sums via ones
      __builtin_amdgcn_s_setprio(1);
#pragma unroll
      for (int c = 0; c < 2; c++) {
        s16x8 vf[4];
#pragma unroll
        for (int j = 0; j < 4; j++)
          vf[j] = *(const s16x8*)&Vs[cur][(j * 16 + l16) * 64 + (((c * 4 + quad) ^ swz) * 8)];
#pragma unroll
        for (int sub = 0; sub < 2; sub++) {
          ol[sub] = __builtin_amdgcn_mfma_f32_16x16x32_bf16(ones, F[sub][c], ol[sub], 0, 0, 0);
#pragma unroll
          for (int j = 0; j < 4; j++)
            o[sub][j] = __builtin_amdgcn_mfma_f32_16x16x32_bf16(vf[j], F[sub][c], o[sub][j], 0, 0, 0);
        }
      }
      __builtin_amdgcn_s_setprio(0);
    }

    __syncthreads();  // drains prefetch (covered by compute) + WAR fence
  }

  // epilogue
  if (kind == 0) {
#pragma unroll
    for (int sub = 0; sub < 2; sub++) {
      const float inv = 1.0f / ol[sub][0];
      const int q = q0w + sub * 16 + l16;
      short* ob = attout + ((size_t)(b * T_ + q) * H_ + h) * 64 + quad * 4;
#pragma unroll
      for (int j = 0; j < 4; j++) {
        s16x4 pk;
#pragma unroll
        for (int r = 0; r < 4; r++) pk[r] = f2bf(o[sub][j][r] * inv);
        *(s16x4*)&ob[16 * j] = pk;
      }
    }
  } else {
    float* sc = scr + (kind == 2 ? 2097152 : 0);
#pragma unroll
    for (int sub = 0; sub < 2; sub++) {
      const int q = q0w + sub * 16 + l16;          // in [1024, 2048)
      const int qi = q - 1024;
      float* sp = sc + ((size_t)(bh * 1024 + qi)) * 64 + quad * 4;
#pragma unroll
      for (int j = 0; j < 4; j++) *(f32x4*)&sp[16 * j] = o[sub][j];
      if (quad == 0) {
        float* lp = (float*)(qkv + (size_t)(b * T_ + q) * E3_ + 2 * E_);
        lp[h + (kind == 2 ? 16 : 0)] = ol[sub][0];
      }
    }
  }
}

// ---------------- combine+normalize for split rows q in [1024,2048) ---------
__global__ void att_norm(const float* __restrict__ scr, const short* __restrict__ qkv,
                         short* __restrict__ attb) {
  const int bid = blockIdx.x;
  const int bh2 = bid & 31;              // bid%8 = bh%8 -> XCD-local scratch
  const int g   = bid >> 5;              // 0..63
  const int tid = threadIdx.x;
  const int qi  = g * 16 + (tid >> 4);
  const int d0  = (tid & 15) * 4;
  const int b = bh2 >> 4, h = bh2 & 15;
  const size_t idx = ((size_t)bh2 * 1024 + qi) * 64 + d0;
  const f32x4 a = *(const f32x4*)&scr[idx];
  const f32x4 c = *(const f32x4*)&scr[2097152 + idx];
  const float* lp = (const float*)(qkv + (size_t)(b * T_ + 1024 + qi) * E3_ + 2 * E_);
  const float inv = 1.0f / (lp[h] + lp[16 + h]);
  short* ob = attb + ((size_t)(b * T_ + 1024 + qi) * H_ + h) * 64 + d0;
  s16x4 pk;
#pragma unroll
  for (int r = 0; r < 4; r++) pk[r] = f2bf((a[r] + c[r]) * inv);
  *(s16x4*)ob = pk;
}

// ---------------- launch -----------------------------------------------------
extern "C" void kernel_launch(void* const* d_in, const int* in_sizes, int n_in,
                              void* d_out, int out_size, void* d_ws, size_t ws_size,
                              hipStream_t stream) {
  const float* x     = (const float*)d_in[0];   // [4096, 1024] fp32
  const float* wqkv  = (const float*)d_in[1];   // [3072, 1024] fp32
  const float* wproj = (const float*)d_in[2];   // [1024, 1024] fp32

  if (ws_size < 58720256u) return;
  short* ws     = (short*)d_ws;
  short* xb     = ws;                    // 4096*1024
  short* wqkvb  = xb + 4194304;          // 3072*1024
  short* wprojb = wqkvb + 3145728;       // 1024*1024
  short* qkv    = wprojb + 1048576;      // 4096*3072 (V third = l-scratch)
  short* vt     = qkv + 12582912;        // 2*16*64*2048
  short* attb   = vt + 4194304;          // 4096*1024

  castk_all<<<8192, 256, 0, stream>>>(x, wqkv, wproj, xb, wqkvb, wprojb);
  gemm_nt_128<2><<<dim3(24, 32), 256, 0, stream>>>(xb, wqkvb, qkv, vt, 4096, 3072, 1024);
  // d_out doubles as f32 partial-O scratch (16MB) until the proj GEMM runs
  attn_kernel<<<dim3(768), 256, 0, stream>>>(qkv, vt, attb, (float*)d_out);
  att_norm<<<dim3(2048), 256, 0, stream>>>((const float*)d_out, qkv, attb);
  gemm_nt_128<0><<<dim3(8, 32), 256, 0, stream>>>(attb, wprojb, d_out, nullptr, 4096, 1024, 1024);
}

// Round 11
// 174.296 us; speedup vs baseline: 1.0433x; 1.0104x over previous
//
#include <hip/hip_runtime.h>
#include <stdint.h>
#include <stddef.h>

typedef __attribute__((ext_vector_type(8))) short s16x8;
typedef __attribute__((ext_vector_type(4))) short s16x4;
typedef __attribute__((ext_vector_type(4))) float f32x4;

#define B_  2
#define T_  2048
#define E_  1024
#define H_  16
#define E3_ 3072

// fp32 -> bf16, round-to-nearest-even
__device__ __forceinline__ short f2bf(float f) {
  union { float f; uint32_t u; } v; v.f = f;
  uint32_t u = v.u;
  return (short)((u + 0x7FFFu + ((u >> 16) & 1u)) >> 16);
}

// async global->LDS, 16B per lane; lds dest = wave-uniform base + lane*16
__device__ __forceinline__ void gload_lds16(const short* g, short* l) {
  __builtin_amdgcn_global_load_lds(
      (__attribute__((address_space(1))) void*)(const_cast<short*>(g)),
      (__attribute__((address_space(3))) void*)(l), 16, 0, 0);
}

// ---------------- merged cast kernel (x, w_qkv, w_proj in one launch) -------
// Q-rows of w_qkv (first E rows) pre-scaled by log2(e)/8 so attention can
// call exp2f directly on MFMA output.
__global__ void castk_all(const float* __restrict__ x, const float* __restrict__ wqkv,
                          const float* __restrict__ wproj, short* __restrict__ xb,
                          short* __restrict__ wqkvb, short* __restrict__ wprojb) {
  const int bid = blockIdx.x;
  const float* in; short* out; int i; float sc = 1.0f;
  if (bid < 4096)      { in = x;     out = xb;     i = bid * 256 + threadIdx.x; }
  else if (bid < 7168) { in = wqkv;  out = wqkvb;  i = (bid - 4096) * 256 + threadIdx.x;
                         if (i < 262144) sc = 0.18033688011112042f; }
  else                 { in = wproj; out = wprojb; i = (bid - 7168) * 256 + threadIdx.x; }
  const float4 v = ((const float4*)in)[i];
  s16x4 o;
  o[0] = f2bf(v.x * sc); o[1] = f2bf(v.y * sc);
  o[2] = f2bf(v.z * sc); o[3] = f2bf(v.w * sc);
  ((s16x4*)out)[i] = o;
}

// ---------------- NT GEMM: C[M,N] = A[M,K] * B[N,K]^T (bf16 in, fp32 acc) ---
template <int MODE>
__global__ void gemm_nt_128(const short* __restrict__ A, const short* __restrict__ B,
                            void* __restrict__ Cv, short* __restrict__ vt,
                            int M, int N, int K) {
  __shared__ short As[128 * 32];
  __shared__ short Bs[128 * 32];
  const int tid  = threadIdx.x;
  const int lane = tid & 63;
  const int w    = tid >> 6;
  const int quad = lane >> 4;
  const int l16  = lane & 15;
  const int wm   = (w >> 1) * 64;
  const int wn   = (w & 1) * 64;
  const int bm   = blockIdx.y * 128;
  const int bn   = blockIdx.x * 128;

  f32x4 acc[4][4];
#pragma unroll
  for (int i = 0; i < 4; i++)
#pragma unroll
    for (int j = 0; j < 4; j++) acc[i][j] = (f32x4){0.f, 0.f, 0.f, 0.f};

  const int srow = w * 32 + (lane >> 2);
  const int scol = (lane & 3) * 8;
  const short* gA = A + (size_t)(bm + srow) * K + scol;
  const short* gB = B + (size_t)(bn + srow) * K + scol;
  short* lA = As + (w * 32) * 32;
  short* lB = Bs + (w * 32) * 32;

  for (int k0 = 0; k0 < K; k0 += 32) {
    __syncthreads();
    gload_lds16(gA + k0,          lA);
    gload_lds16(gA + 16 * K + k0, lA + 16 * 32);
    gload_lds16(gB + k0,          lB);
    gload_lds16(gB + 16 * K + k0, lB + 16 * 32);
    __syncthreads();

    s16x8 a[4], b[4];
#pragma unroll
    for (int i = 0; i < 4; i++)
      a[i] = *(const s16x8*)&As[(wm + i * 16 + l16) * 32 + quad * 8];
#pragma unroll
    for (int j = 0; j < 4; j++)
      b[j] = *(const s16x8*)&Bs[(wn + j * 16 + l16) * 32 + quad * 8];
#pragma unroll
    for (int i = 0; i < 4; i++)
#pragma unroll
      for (int j = 0; j < 4; j++)
        acc[i][j] = __builtin_amdgcn_mfma_f32_16x16x32_bf16(a[i], b[j], acc[i][j], 0, 0, 0);
  }

  if (MODE == 2 && bn >= 2 * E_) {
#pragma unroll
    for (int i = 0; i < 4; i++) {
      const int token = bm + wm + i * 16 + quad * 4;
      const int bb = token >> 11, t = token & (T_ - 1);
#pragma unroll
      for (int j = 0; j < 4; j++) {
        const int col = bn + wn + j * 16 + l16 - 2 * E_;  // h*64 + d
        s16x4 pk;
#pragma unroll
        for (int r = 0; r < 4; r++) pk[r] = f2bf(acc[i][j][r]);
        *(s16x4*)&vt[((size_t)(bb * H_ + (col >> 6)) * 64 + (col & 63)) * T_ + t] = pk;
      }
    }
  } else {
#pragma unroll
    for (int i = 0; i < 4; i++) {
      const int row0 = bm + wm + i * 16 + quad * 4;
#pragma unroll
      for (int j = 0; j < 4; j++) {
        const int col = bn + wn + j * 16 + l16;
#pragma unroll
        for (int r = 0; r < 4; r++) {
          const size_t idx = (size_t)(row0 + r) * N + col;
          if (MODE == 2) ((short*)Cv)[idx] = f2bf(acc[i][j][r]);
          else           ((float*)Cv)[idx] = acc[i][j][r];
        }
      }
    }
  }
}

// ---------------- flash attention -------------------------------------------
// R10 (resubmitted after infra timeout; never measured) = R4 body VERBATIM
// (best verified per-step efficiency: 16q/wave, 4-wave 64q blocks, sigma
// K-store perm, tau diag mask, cvt_pk+permlane in-register P transpose,
// ones-MFMA row sums, R4 prefetch placement, 32KB LDS) + R9's PROVEN
// split/combine machinery + a refill grid:
//  * Items: qt 0..15 full (1..16 steps); qt 16..31 split mid into head/tail
//    (8..16 steps) -> ALL items <=16 steps. R4's defect was the 33-step
//    critical-path item (per-CU lifetimes {32,17,16,1}, occupancy 25%).
//  * Split rows = q in [1024,2048) exactly -> R9's verified scratch layout
//    (raw f32 O in d_out, row-sums in dead V-third of qkv) + verified
//    att_norm combine. No-max softmax makes partials additive.
//  * Grid 48 items x 32 bh = 1536 blocks; LDS 32KB -> 5 blocks/CU (160KB
//    exact): 1280 resident + 256 refill (work-conserving; R8's queue goal
//    WITHOUT losing XCD locality: bid = item*32+bh -> XCD = bh%8).
//  * aorder = LPT (longest-first); shortest items last = refill tail.
__device__ const unsigned char aorder[48] = {
  // value = kind*32 + qt; kind 0=full, 1=head [0,hq), 2=tail [hq,qt]
  15, 63, 95, 62,                  // len 16
  14, 94, 61, 93, 60,              // len 15
  13, 92, 59, 91, 58,              // len 14
  12, 90, 57, 89, 56,              // len 13
  11, 88, 55, 87, 54,              // len 12
  10, 86, 53, 85, 52,              // len 11
   9, 84, 51, 83, 50,              // len 10
   8, 82, 49, 81, 48,              // len 9
   7, 80,                          // len 8
   6,  5,  4,  3,  2,  1,  0       // len 7..1
};

__global__ void __launch_bounds__(256, 5)
attn_kernel(short* qkv, const short* __restrict__ vt,
            short* __restrict__ attout, float* __restrict__ scr) {
  __shared__ short Ks[2][64 * 64];  // [kv_pos][d], sigma row order
  __shared__ short Vs[2][64 * 64];  // [d][kv], linear kv
  const int tid  = threadIdx.x;
  const int lane = tid & 63;
  const int w    = tid >> 6;
  const int quad = lane >> 4;
  const int l16  = lane & 15;
  const int bh = blockIdx.x & 31;
  const int b = bh >> 4, h = bh & 15;
  const int e = aorder[blockIdx.x >> 5];
  const int qt = e & 31, kind = e >> 5;
  const int hq = (qt + 2) >> 1;                 // head step count
  const int t0 = (kind == 2) ? hq : 0;
  const int t1 = (kind == 1) ? (hq - 1) : qt;   // head never reaches diag
  const int q0w = qt * 64 + w * 16;
  const float NEG_INF = -__builtin_inff();

  const int srl = lane >> 3;
  const int sgc = ((lane & 7) ^ srl) * 8;
  const short* gK = qkv + (size_t)(b * T_) * E3_ + E_ + h * 64 + sgc;
  const short* gV = vt + (size_t)(bh * 64) * T_ + sgc;
  const int swz = (l16 & 7);

  s16x8 ones;
#pragma unroll
  for (int i = 0; i < 8; i++) ones[i] = (short)0x3F80;  // bf16 1.0

  auto stage = [&](int kv0s, int bf) {
#pragma unroll
    for (int i = 0; i < 2; i++) {
      const int r8 = w * 16 + i * 8;          // LDS row-chunk base
      const int rowp = r8 + srl;              // LDS row position
      // sigma: swap bits 2,3 of row index (K source only; V stays linear)
      const int rowk = (rowp & ~12) | ((rowp & 4) << 1) | ((rowp & 8) >> 1);
      gload_lds16(gK + (size_t)(kv0s + rowk) * E3_, &Ks[bf][r8 * 64]);
      gload_lds16(gV + (size_t)rowp * T_ + kv0s,    &Vs[bf][r8 * 64]);
    }
  };

  // Q B-fragments (pre-scaled): B[n=l16][k=quad*8+j], two k-chunks
  const short* qbase = qkv + (size_t)(b * T_ + q0w + l16) * E3_ + h * 64 + quad * 8;
  const s16x8 qf0 = *(const s16x8*)(qbase);
  const s16x8 qf1 = *(const s16x8*)(qbase + 32);

  f32x4 o[4]; f32x4 ol = (f32x4){0.f, 0.f, 0.f, 0.f};
#pragma unroll
  for (int j = 0; j < 4; j++) o[j] = (f32x4){0.f, 0.f, 0.f, 0.f};

  // prologue: stage first tile into buffer 0
  stage(t0 * 64, 0);
  __syncthreads();

  for (int t = t0, g = 0; t <= t1; t++, g++) {
    const int cur = g & 1;

    // K A-fragments for this step
    s16x8 kf[2][4];
#pragma unroll
    for (int c = 0; c < 2; c++)
#pragma unroll
      for (int j = 0; j < 4; j++)
        kf[c][j] = *(const s16x8*)&Ks[cur][(j * 16 + l16) * 64 + (((c * 4 + quad) ^ swz) * 8)];

    // prefetch next tile's DMA (hidden under this step's compute)
    if (t + 1 <= t1) stage((t + 1) * 64, cur ^ 1);

    // S^T tile: s[j][r] = score[kv_pos = 64t+16j+4quad+r][q = q0w+l16]
    f32x4 s[4];
#pragma unroll
    for (int j = 0; j < 4; j++) s[j] = (f32x4){0.f, 0.f, 0.f, 0.f};
    __builtin_amdgcn_s_setprio(1);
#pragma unroll
    for (int c = 0; c < 2; c++)
#pragma unroll
      for (int j = 0; j < 4; j++)
        s[j] = __builtin_amdgcn_mfma_f32_16x16x32_bf16(kf[c][j], c == 0 ? qf0 : qf1, s[j], 0, 0, 0);
    __builtin_amdgcn_s_setprio(0);

    // mask only on the diagonal step; actual kv = 16j + 4*tau(quad) + r
    if (t == qt) {
      const int tq4 = ((quad & 1) << 3) | ((quad >> 1) << 2);
#pragma unroll
      for (int j = 0; j < 4; j++)
#pragma unroll
        for (int r = 0; r < 4; r++)
          if (j * 16 + tq4 + r > w * 16 + l16) s[j][r] = NEG_INF;
    }

    // exp2 in place
#pragma unroll
    for (int j = 0; j < 4; j++) {
      s[j][0] = exp2f(s[j][0]); s[j][1] = exp2f(s[j][1]);
      s[j][2] = exp2f(s[j][2]); s[j][3] = exp2f(s[j][3]);
    }

    // pack row pairs -> bf16 dwords (dst.lo = src0)
    int dj[4][2];
#pragma unroll
    for (int j = 0; j < 4; j++) {
      asm("v_cvt_pk_bf16_f32 %0, %1, %2" : "=v"(dj[j][0]) : "v"(s[j][0]), "v"(s[j][1]));
      asm("v_cvt_pk_bf16_f32 %0, %1, %2" : "=v"(dj[j][1]) : "v"(s[j][2]), "v"(s[j][3]));
    }

    // 2x permlane32_swap per kv32 chunk -> B-operand fragments in actual-kv order
    s16x8 F[2];
#pragma unroll
    for (int c = 0; c < 2; c++) {
      int x0 = dj[2 * c][0], y0 = dj[2 * c + 1][0];
      int x1 = dj[2 * c][1], y1 = dj[2 * c + 1][1];
      asm("v_permlane32_swap_b32 %0, %1" : "+v"(x0), "+v"(y0));
      asm("v_permlane32_swap_b32 %0, %1" : "+v"(x1), "+v"(y1));
      union { int i4[4]; s16x8 v; } u;
      u.i4[0] = x0; u.i4[1] = x1; u.i4[2] = y0; u.i4[3] = y1;
      F[c] = u.v;
    }

    // O^T += V^T P^T ; row sums via ones-MFMA (every reg = sum of lane's q)
    __builtin_amdgcn_s_setprio(1);
#pragma unroll
    for (int c = 0; c < 2; c++) {
      ol = __builtin_amdgcn_mfma_f32_16x16x32_bf16(ones, F[c], ol, 0, 0, 0);
#pragma unroll
      for (int j = 0; j < 4; j++) {
        const s16x8 vf = *(const s16x8*)&Vs[cur][(j * 16 + l16) * 64 + (((c * 4 + quad) ^ swz) * 8)];
        o[j] = __builtin_amdgcn_mfma_f32_16x16x32_bf16(vf, F[c], o[j], 0, 0, 0);
      }
    }
    __builtin_amdgcn_s_setprio(0);

    __syncthreads();  // drains prefetch (covered by compute) + WAR fence
  }

  // epilogue: lane owns q = q0w + l16; o[j][r] = O[q][d = 16j+4quad+r]
  if (kind == 0) {
    const float inv = 1.0f / ol[0];
    const int q = q0w + l16;
    short* ob = attout + ((size_t)(b * T_ + q) * H_ + h) * 64 + quad * 4;
#pragma unroll
    for (int j = 0; j < 4; j++) {
      s16x4 pk;
#pragma unroll
      for (int r = 0; r < 4; r++) pk[r] = f2bf(o[j][r] * inv);
      *(s16x4*)&ob[16 * j] = pk;
    }
  } else {
    // partial: raw f32 O to scratch + row-sum to dead V-third (R9-verified)
    const int q  = q0w + l16;            // in [1024, 2048)
    const int qi = q - 1024;
    float* sp = scr + (kind == 2 ? 2097152 : 0)
                    + ((size_t)(bh * 1024 + qi)) * 64 + quad * 4;
#pragma unroll
    for (int j = 0; j < 4; j++) *(f32x4*)&sp[16 * j] = o[j];
    if (quad == 0) {
      float* lp = (float*)(qkv + (size_t)(b * T_ + q) * E3_ + 2 * E_);
      lp[h + (kind == 2 ? 16 : 0)] = ol[0];
    }
  }
}

// ---------------- combine+normalize for split rows q in [1024,2048) ---------
__global__ void att_norm(const float* __restrict__ scr, const short* __restrict__ qkv,
                         short* __restrict__ attb) {
  const int bid = blockIdx.x;
  const int bh2 = bid & 31;              // bid%8 = bh%8 -> XCD-local scratch
  const int g   = bid >> 5;              // 0..63
  const int tid = threadIdx.x;
  const int qi  = g * 16 + (tid >> 4);
  const int d0  = (tid & 15) * 4;
  const int b = bh2 >> 4, h = bh2 & 15;
  const size_t idx = ((size_t)bh2 * 1024 + qi) * 64 + d0;
  const f32x4 a = *(const f32x4*)&scr[idx];
  const f32x4 c = *(const f32x4*)&scr[2097152 + idx];
  const float* lp = (const float*)(qkv + (size_t)(b * T_ + 1024 + qi) * E3_ + 2 * E_);
  const float inv = 1.0f / (lp[h] + lp[16 + h]);
  short* ob = attb + ((size_t)(b * T_ + 1024 + qi) * H_ + h) * 64 + d0;
  s16x4 pk;
#pragma unroll
  for (int r = 0; r < 4; r++) pk[r] = f2bf((a[r] + c[r]) * inv);
  *(s16x4*)ob = pk;
}

// ---------------- launch -----------------------------------------------------
extern "C" void kernel_launch(void* const* d_in, const int* in_sizes, int n_in,
                              void* d_out, int out_size, void* d_ws, size_t ws_size,
                              hipStream_t stream) {
  const float* x     = (const float*)d_in[0];   // [4096, 1024] fp32
  const float* wqkv  = (const float*)d_in[1];   // [3072, 1024] fp32
  const float* wproj = (const float*)d_in[2];   // [1024, 1024] fp32

  if (ws_size < 58720256u) return;
  short* ws     = (short*)d_ws;
  short* xb     = ws;                    // 4096*1024
  short* wqkvb  = xb + 4194304;          // 3072*1024
  short* wprojb = wqkvb + 3145728;       // 1024*1024
  short* qkv    = wprojb + 1048576;      // 4096*3072 (V third = rowsum scratch)
  short* vt     = qkv + 12582912;        // 2*16*64*2048
  short* attb   = vt + 4194304;          // 4096*1024

  castk_all<<<8192, 256, 0, stream>>>(x, wqkv, wproj, xb, wqkvb, wprojb);
  gemm_nt_128<2><<<dim3(24, 32), 256, 0, stream>>>(xb, wqkvb, qkv, vt, 4096, 3072, 1024);
  // d_out doubles as f32 partial-O scratch (16.8MB) until the proj GEMM runs
  attn_kernel<<<dim3(1536), 256, 0, stream>>>(qkv, vt, attb, (float*)d_out);
  att_norm<<<dim3(2048), 256, 0, stream>>>((const float*)d_out, qkv, attb);
  gemm_nt_128<0><<<dim3(8, 32), 256, 0, stream>>>(attb, wprojb, d_out, nullptr, 4096, 1024, 1024);
}

// Round 12
// 162.897 us; speedup vs baseline: 1.1163x; 1.0700x over previous
//
#include <hip/hip_runtime.h>
#include <stdint.h>
#include <stddef.h>

typedef __attribute__((ext_vector_type(8))) short s16x8;
typedef __attribute__((ext_vector_type(4))) short s16x4;
typedef __attribute__((ext_vector_type(4))) float f32x4;

#define B_  2
#define T_  2048
#define E_  1024
#define H_  16
#define E3_ 3072

// fp32 -> bf16, round-to-nearest-even
__device__ __forceinline__ short f2bf(float f) {
  union { float f; uint32_t u; } v; v.f = f;
  uint32_t u = v.u;
  return (short)((u + 0x7FFFu + ((u >> 16) & 1u)) >> 16);
}

// async global->LDS, 16B per lane; lds dest = wave-uniform base + lane*16
__device__ __forceinline__ void gload_lds16(const short* g, short* l) {
  __builtin_amdgcn_global_load_lds(
      (__attribute__((address_space(1))) void*)(const_cast<short*>(g)),
      (__attribute__((address_space(3))) void*)(l), 16, 0, 0);
}

// ---------------- merged cast kernel (x, w_qkv, w_proj in one launch) -------
// Q-rows of w_qkv (first E rows) pre-scaled by log2(e)/8 so attention can
// use raw v_exp_f32 directly on MFMA output.
__global__ void castk_all(const float* __restrict__ x, const float* __restrict__ wqkv,
                          const float* __restrict__ wproj, short* __restrict__ xb,
                          short* __restrict__ wqkvb, short* __restrict__ wprojb) {
  const int bid = blockIdx.x;
  const float* in; short* out; int i; float sc = 1.0f;
  if (bid < 4096)      { in = x;     out = xb;     i = bid * 256 + threadIdx.x; }
  else if (bid < 7168) { in = wqkv;  out = wqkvb;  i = (bid - 4096) * 256 + threadIdx.x;
                         if (i < 262144) sc = 0.18033688011112042f; }
  else                 { in = wproj; out = wprojb; i = (bid - 7168) * 256 + threadIdx.x; }
  const float4 v = ((const float4*)in)[i];
  s16x4 o;
  o[0] = f2bf(v.x * sc); o[1] = f2bf(v.y * sc);
  o[2] = f2bf(v.z * sc); o[3] = f2bf(v.w * sc);
  ((s16x4*)out)[i] = o;
}

// ---------------- NT GEMM: C[M,N] = A[M,K] * B[N,K]^T (bf16 in, fp32 acc) ---
// MODE 0: fp32 output, plain. MODE 2: qkv mode — bf16 output; V columns
// (col >= 2E) are written TRANSPOSED into vt[b,h,d,t] (packed s16x4 over 4
// consecutive t), Q/K columns go to the qkv buffer. Fuses the old vtrans.
template <int MODE>
__global__ void gemm_nt_128(const short* __restrict__ A, const short* __restrict__ B,
                            void* __restrict__ Cv, short* __restrict__ vt,
                            int M, int N, int K) {
  __shared__ short As[128 * 32];
  __shared__ short Bs[128 * 32];
  const int tid  = threadIdx.x;
  const int lane = tid & 63;
  const int w    = tid >> 6;
  const int quad = lane >> 4;
  const int l16  = lane & 15;
  const int wm   = (w >> 1) * 64;
  const int wn   = (w & 1) * 64;
  const int bm   = blockIdx.y * 128;
  const int bn   = blockIdx.x * 128;

  f32x4 acc[4][4];
#pragma unroll
  for (int i = 0; i < 4; i++)
#pragma unroll
    for (int j = 0; j < 4; j++) acc[i][j] = (f32x4){0.f, 0.f, 0.f, 0.f};

  const int srow = w * 32 + (lane >> 2);
  const int scol = (lane & 3) * 8;
  const short* gA = A + (size_t)(bm + srow) * K + scol;
  const short* gB = B + (size_t)(bn + srow) * K + scol;
  short* lA = As + (w * 32) * 32;
  short* lB = Bs + (w * 32) * 32;

  for (int k0 = 0; k0 < K; k0 += 32) {
    __syncthreads();
    gload_lds16(gA + k0,          lA);
    gload_lds16(gA + 16 * K + k0, lA + 16 * 32);
    gload_lds16(gB + k0,          lB);
    gload_lds16(gB + 16 * K + k0, lB + 16 * 32);
    __syncthreads();

    s16x8 a[4], b[4];
#pragma unroll
    for (int i = 0; i < 4; i++)
      a[i] = *(const s16x8*)&As[(wm + i * 16 + l16) * 32 + quad * 8];
#pragma unroll
    for (int j = 0; j < 4; j++)
      b[j] = *(const s16x8*)&Bs[(wn + j * 16 + l16) * 32 + quad * 8];
#pragma unroll
    for (int i = 0; i < 4; i++)
#pragma unroll
      for (int j = 0; j < 4; j++)
        acc[i][j] = __builtin_amdgcn_mfma_f32_16x16x32_bf16(a[i], b[j], acc[i][j], 0, 0, 0);
  }

  if (MODE == 2 && bn >= 2 * E_) {
    // V block: write transposed to vt[b,h,d,t], 4 consecutive t per store
#pragma unroll
    for (int i = 0; i < 4; i++) {
      const int token = bm + wm + i * 16 + quad * 4;
      const int bb = token >> 11, t = token & (T_ - 1);
#pragma unroll
      for (int j = 0; j < 4; j++) {
        const int col = bn + wn + j * 16 + l16 - 2 * E_;  // h*64 + d
        s16x4 pk;
#pragma unroll
        for (int r = 0; r < 4; r++) pk[r] = f2bf(acc[i][j][r]);
        *(s16x4*)&vt[((size_t)(bb * H_ + (col >> 6)) * 64 + (col & 63)) * T_ + t] = pk;
      }
    }
  } else {
#pragma unroll
    for (int i = 0; i < 4; i++) {
      const int row0 = bm + wm + i * 16 + quad * 4;
#pragma unroll
      for (int j = 0; j < 4; j++) {
        const int col = bn + wn + j * 16 + l16;
#pragma unroll
        for (int r = 0; r < 4; r++) {
          const size_t idx = (size_t)(row0 + r) * N + col;
          if (MODE == 2) ((short*)Cv)[idx] = f2bf(acc[i][j][r]);
          else           ((float*)Cv)[idx] = acc[i][j][r];
        }
      }
    }
  }
}

// ---------------- flash attention -------------------------------------------
// R12 = R4 VERBATIM (best verified config, total 167.7us) with ONE change:
//   exp2f() -> __builtin_amdgcn_exp2f() (raw v_exp_f32).
// Theory: R4/R7 counters show VALUBusy ~40% = ~550 VALU cyc per block-step
// per SIMD, ~4x the hand-count of the visible VALU work. Without -ffast-math,
// exp2f lowers to the __ocml_exp2_f32 library wrapper (~8-12 instructions for
// range/edge handling); at 16 calls/wave-step that is the dominant VALU cost.
// The raw intrinsic is a single quarter-rate v_exp_f32. Inputs are <= 0 down
// to -inf; v_exp_f32(-inf) = 0 exactly; denormal flush irrelevant at bf16.
// Everything else (grid, LPT snake, sigma K-store perm, tau diag mask,
// cvt_pk+permlane in-register P transpose, ones-MFMA row sums, prefetch
// placement, 32KB LDS, setprio) is byte-identical to R4 for attribution.
// R11 lesson: split/combine grid nets +6.6us vs R4 (machinery cost > gain).
__global__ void __launch_bounds__(256, 4)
attn_kernel(const short* __restrict__ qkv, const short* __restrict__ vt,
            short* __restrict__ attout) {
  __shared__ short Ks[2][64 * 64];  // [kv_pos][d], 16B-chunk swizzled, sigma row order
  __shared__ short Vs[2][64 * 64];  // [d][kv], 16B-chunk swizzled, linear kv
  const int tid  = threadIdx.x;
  const int lane = tid & 63;
  const int w    = tid >> 6;
  const int quad = lane >> 4;
  const int l16  = lane & 15;
  const int bh = blockIdx.x;
  const int b = bh >> 4, h = bh & 15;
  // LPT snake mapping: longest q-tiles dispatched first, per-CU sum uniform
  const int ya = blockIdx.y & 7, yb = blockIdx.y >> 3;
  const int qt = (3 - yb) * 8 + ((yb & 1) ? ya : (7 - ya));
  const int q0b = qt * 64;
  const int q0w = q0b + w * 16;
  const float NEG_INF = -__builtin_inff();

  const int srl = lane >> 3;
  const int sgc = ((lane & 7) ^ srl) * 8;
  const short* gK = qkv + (size_t)(b * T_) * E3_ + E_ + h * 64 + sgc;
  const short* gV = vt + (size_t)(bh * 64) * T_ + sgc;
  const int swz = (l16 & 7);

  s16x8 ones;
#pragma unroll
  for (int i = 0; i < 8; i++) ones[i] = (short)0x3F80;  // bf16 1.0

  auto stage = [&](int kv0s, int bf) {
#pragma unroll
    for (int i = 0; i < 2; i++) {
      const int r8 = w * 16 + i * 8;          // LDS row-chunk base
      const int rowp = r8 + srl;              // LDS row position
      // sigma: swap bits 2,3 of row index (K source only; V stays linear)
      const int rowk = (rowp & ~12) | ((rowp & 4) << 1) | ((rowp & 8) >> 1);
      gload_lds16(gK + (size_t)(kv0s + rowk) * E3_, &Ks[bf][r8 * 64]);
      gload_lds16(gV + (size_t)rowp * T_ + kv0s,    &Vs[bf][r8 * 64]);
    }
  };

  // Q B-fragments (pre-scaled): B[n=l16][k=quad*8+j], two k-chunks
  const short* qbase = qkv + (size_t)(b * T_ + q0w + l16) * E3_ + h * 64 + quad * 8;
  const s16x8 qf0 = *(const s16x8*)(qbase);
  const s16x8 qf1 = *(const s16x8*)(qbase + 32);

  f32x4 o[4]; f32x4 ol = (f32x4){0.f, 0.f, 0.f, 0.f};
#pragma unroll
  for (int j = 0; j < 4; j++) o[j] = (f32x4){0.f, 0.f, 0.f, 0.f};

  // prologue: stage kv tile 0 into buffer 0
  stage(0, 0);
  __syncthreads();

  for (int kv0 = 0, g = 0; kv0 <= q0b; kv0 += 64, g++) {
    const int cur = g & 1;

    // K A-fragments for this step
    s16x8 kf[2][4];
#pragma unroll
    for (int c = 0; c < 2; c++)
#pragma unroll
      for (int j = 0; j < 4; j++)
        kf[c][j] = *(const s16x8*)&Ks[cur][(j * 16 + l16) * 64 + (((c * 4 + quad) ^ swz) * 8)];

    // prefetch next tile's DMA (hidden under this step's compute)
    if (kv0 + 64 <= q0b) stage(kv0 + 64, cur ^ 1);

    // S^T tile: s[j][r] = score[kv_pos = 16j+4quad+r][q = q0w+l16]
    f32x4 s[4];
#pragma unroll
    for (int j = 0; j < 4; j++) s[j] = (f32x4){0.f, 0.f, 0.f, 0.f};
    __builtin_amdgcn_s_setprio(1);
#pragma unroll
    for (int c = 0; c < 2; c++)
#pragma unroll
      for (int j = 0; j < 4; j++)
        s[j] = __builtin_amdgcn_mfma_f32_16x16x32_bf16(kf[c][j], c == 0 ? qf0 : qf1, s[j], 0, 0, 0);
    __builtin_amdgcn_s_setprio(0);

    // mask only on the diagonal step; actual kv = 16j + 4*tau(quad) + r
    if (kv0 == q0b) {
      const int tq4 = ((quad & 1) << 3) | ((quad >> 1) << 2);
#pragma unroll
      for (int j = 0; j < 4; j++)
#pragma unroll
        for (int r = 0; r < 4; r++)
          if (j * 16 + tq4 + r > w * 16 + l16) s[j][r] = NEG_INF;
    }

    // exp2 in place — raw v_exp_f32 (single quarter-rate instruction each)
#pragma unroll
    for (int j = 0; j < 4; j++) {
      s[j][0] = __builtin_amdgcn_exp2f(s[j][0]);
      s[j][1] = __builtin_amdgcn_exp2f(s[j][1]);
      s[j][2] = __builtin_amdgcn_exp2f(s[j][2]);
      s[j][3] = __builtin_amdgcn_exp2f(s[j][3]);
    }

    // pack row pairs -> bf16 dwords (dst.lo = src0)
    int dj[4][2];
#pragma unroll
    for (int j = 0; j < 4; j++) {
      asm("v_cvt_pk_bf16_f32 %0, %1, %2" : "=v"(dj[j][0]) : "v"(s[j][0]), "v"(s[j][1]));
      asm("v_cvt_pk_bf16_f32 %0, %1, %2" : "=v"(dj[j][1]) : "v"(s[j][2]), "v"(s[j][3]));
    }

    // 2x permlane32_swap per kv32 chunk -> B-operand fragments in actual-kv order
    s16x8 F[2];
#pragma unroll
    for (int c = 0; c < 2; c++) {
      int x0 = dj[2 * c][0], y0 = dj[2 * c + 1][0];
      int x1 = dj[2 * c][1], y1 = dj[2 * c + 1][1];
      asm("v_permlane32_swap_b32 %0, %1" : "+v"(x0), "+v"(y0));
      asm("v_permlane32_swap_b32 %0, %1" : "+v"(x1), "+v"(y1));
      union { int i4[4]; s16x8 v; } u;
      u.i4[0] = x0; u.i4[1] = x1; u.i4[2] = y0; u.i4[3] = y1;
      F[c] = u.v;
    }

    // O^T += V^T P^T ; row sums via ones-MFMA (every reg = sum of lane's q)
    __builtin_amdgcn_s_setprio(1);
#pragma unroll
    for (int c = 0; c < 2; c++) {
      ol = __builtin_amdgcn_mfma_f32_16x16x32_bf16(ones, F[c], ol, 0, 0, 0);
#pragma unroll
      for (int j = 0; j < 4; j++) {
        const s16x8 vf = *(const s16x8*)&Vs[cur][(j * 16 + l16) * 64 + (((c * 4 + quad) ^ swz) * 8)];
        o[j] = __builtin_amdgcn_mfma_f32_16x16x32_bf16(vf, F[c], o[j], 0, 0, 0);
      }
    }
    __builtin_amdgcn_s_setprio(0);

    __syncthreads();  // drains prefetch (covered by compute) + WAR fence
  }

  // epilogue: lane owns q = q0w + l16; o[j][r] = O[q][d = 16j+4quad+r]
  const float inv = 1.0f / ol[0];
  const int q = q0w + l16;
  short* ob = attout + ((size_t)(b * T_ + q) * H_ + h) * 64 + quad * 4;
#pragma unroll
  for (int j = 0; j < 4; j++) {
    s16x4 pk;
#pragma unroll
    for (int r = 0; r < 4; r++) pk[r] = f2bf(o[j][r] * inv);
    *(s16x4*)&ob[16 * j] = pk;
  }
}

// ---------------- launch -----------------------------------------------------
extern "C" void kernel_launch(void* const* d_in, const int* in_sizes, int n_in,
                              void* d_out, int out_size, void* d_ws, size_t ws_size,
                              hipStream_t stream) {
  const float* x     = (const float*)d_in[0];   // [4096, 1024] fp32
  const float* wqkv  = (const float*)d_in[1];   // [3072, 1024] fp32
  const float* wproj = (const float*)d_in[2];   // [1024, 1024] fp32

  if (ws_size < 58720256u) return;
  short* ws     = (short*)d_ws;
  short* xb     = ws;                    // 4096*1024
  short* wqkvb  = xb + 4194304;          // 3072*1024
  short* wprojb = wqkvb + 3145728;       // 1024*1024
  short* qkv    = wprojb + 1048576;      // 4096*3072 (V third unused)
  short* vt     = qkv + 12582912;        // 2*16*64*2048
  short* attb   = vt + 4194304;          // 4096*1024

  castk_all<<<8192, 256, 0, stream>>>(x, wqkv, wproj, xb, wqkvb, wprojb);
  gemm_nt_128<2><<<dim3(24, 32), 256, 0, stream>>>(xb, wqkvb, qkv, vt, 4096, 3072, 1024);
  attn_kernel<<<dim3(32, 32), 256, 0, stream>>>(qkv, vt, attb);
  gemm_nt_128<0><<<dim3(8, 32), 256, 0, stream>>>(attb, wprojb, d_out, nullptr, 4096, 1024, 1024);
}